// Round 6
// baseline (159.670 us; speedup 1.0000x reference)
//
#include <hip/hip_runtime.h>
#include <cstdint>

#define BATCH 4
#define TQ 256
#define TK 256
#define DIM 256
#define HD 256

typedef _Float16 f16x8 __attribute__((ext_vector_type(8)));
typedef float f32x4 __attribute__((ext_vector_type(4)));

union U4H8 { uint4 u; f16x8 v; };

__device__ __forceinline__ unsigned short f2h(float f) {
    _Float16 h = (_Float16)f;
    unsigned short u;
    __builtin_memcpy(&u, &h, 2);
    return u;
}

__device__ __forceinline__ uint32_t pk2h(float a, float b) {
    auto r = __builtin_amdgcn_cvt_pkrtz(a, b);
    uint32_t w;
    __builtin_memcpy(&w, &r, 4);
    return w;
}

// Fused prep: blocks 0..255  -> qh = queries@W1[256:]+b1, kh = keys@W1[:256]
//             blocks 256..319 -> W2T[n][c] = (f16)W2[c][n]
// X rows are read via WAVE-UNIFORM addresses -> scalar loads, no LDS.
__global__ __launch_bounds__(256) void prep_all(
    const float* __restrict__ queries, const float* __restrict__ keys,
    const float* __restrict__ W1, const float* __restrict__ b1,
    const float* __restrict__ W2,
    float* __restrict__ qh, float* __restrict__ kh,
    unsigned short* __restrict__ W2T) {
    int i = blockIdx.x;
    int t = threadIdx.x;
    if (i >= 256) {  // ---- W2 transpose ----
        __shared__ float tile[32][33];
        int bi = i - 256;
        int tx = t & 31, ty = t >> 5;
        int tc = (bi & 7) * 32, tn = (bi >> 3) * 32;
#pragma unroll
        for (int r = 0; r < 4; ++r)
            tile[ty + r * 8][tx] = W2[(tc + ty + r * 8) * HD + tn + tx];
        __syncthreads();
#pragma unroll
        for (int r = 0; r < 4; ++r)
            W2T[(tn + ty + r * 8) * HD + tc + tx] = f2h(tile[tx][ty + r * 8]);
        return;
    }
    // ---- qh / kh: 8 output rows per block, thread t = output column ----
    bool isQ = i < 128;
    int r0 = (i & 127) * 8;
    const float* X = (isQ ? queries : keys) + r0 * DIM;   // block-uniform base
    const float* W = W1 + (isQ ? DIM * HD : 0);
    float* O = isQ ? qh : kh;
    float acc[8] = {0.f, 0.f, 0.f, 0.f, 0.f, 0.f, 0.f, 0.f};
#pragma unroll 4
    for (int d = 0; d < DIM; ++d) {
        float w = W[d * HD + t];   // coalesced vector load across t
#pragma unroll
        for (int r = 0; r < 8; ++r)
            acc[r] = fmaf(X[r * DIM + d], w, acc[r]);   // uniform -> s_load
    }
    float bias = isQ ? b1[t] : 0.f;
#pragma unroll
    for (int r = 0; r < 8; ++r) O[(r0 + r) * HD + t] = acc[r] + bias;
}

// One block per (b,q). MFMA score row: 4 k-chunks, double-buffered LDS A,
// B half-resident (s=0..3 in 64 VGPRs) + half streamed per chunk with
// ping-pong prefetch (32-VGPR window). ~220 regs -> 2 waves/SIMD.
// Then masked softmax + PV in-block.
__global__ __launch_bounds__(256, 2) void mlp_attn(
    const float* __restrict__ qh, const float* __restrict__ kh,
    const unsigned short* __restrict__ W2T,
    const float* __restrict__ b2, const float* __restrict__ W3,
    const float* __restrict__ keys,
    const int* __restrict__ qlens, const int* __restrict__ klens,
    float* __restrict__ out) {
    int bid = blockIdx.x;
    int b = bid >> 8;
    int q = bid & 255;
    int t = threadIdx.x;
    float* orow = out + (b * TQ + q) * DIM;
    if (q >= qlens[b]) { orow[t] = 0.f; return; }   // uniform exit, zero row
    int klen = klens[b];
    int nch = (klen + 63) >> 6;   // 2..4 valid 64-wide k chunks

    __shared__ uint4 Afrag[2][8][4][64];  // [buf][k-step][m-tile][lane], 2x32KB
    __shared__ float srow[TK];            // score accumulator -> probs
    __shared__ float red[8];

    int wid = t >> 6, lane = t & 63;
    int col = lane & 15, quad = lane >> 4;

    // ---- B: resident half (s=0..3) = 16 x uint4 = 64 VGPR ----
    // w2r[nt] is ALREADY offset by +quad (lane's c-octet within each k-step);
    // per-step index is s*4 ONLY (adding quad again was R5's correctness bug).
    int nb = wid * 64;
    const uint4* w2r[4];
    uint4 bfr0[4][4];
    float b2v[4], w3v[4];
#pragma unroll
    for (int nt = 0; nt < 4; ++nt) {
        int n = nb + nt * 16 + col;
        w2r[nt] = (const uint4*)(W2T + n * HD) + quad;
#pragma unroll
        for (int s = 0; s < 4; ++s) bfr0[nt][s] = w2r[nt][s * 4];
        b2v[nt] = b2[n];
        w3v[nt] = W3[n];
    }

    // staging role: row p = wid*16 + col, octet = quad.
    // writer lane == destination fragment slot -> contiguous conflict-free
    // ds_write_b128.
    int p = (wid << 4) | col;
    const float* qrow = qh + (b * TQ + q) * HD + quad * 8;  // b1 pre-folded
    const float* kbase = kh + (b * TK) * HD + quad * 8;

    auto stage = [&](int c, int d) {   // stage chunk c into buffer d
        const float* krow = kbase + (c * 64 + p) * HD;
        uint4* dst = &Afrag[d][0][wid][lane];
#pragma unroll 2
        for (int s = 0; s < 8; ++s) {
            const float4 k0 = *(const float4*)(krow + s * 32);
            const float4 k1 = *(const float4*)(krow + s * 32 + 4);
            const float4 q0 = *(const float4*)(qrow + s * 32);
            const float4 q1 = *(const float4*)(qrow + s * 32 + 4);
            uint4 w;
            w.x = pk2h(fmaxf(k0.x + q0.x, 0.f), fmaxf(k0.y + q0.y, 0.f));
            w.y = pk2h(fmaxf(k0.z + q0.z, 0.f), fmaxf(k0.w + q0.w, 0.f));
            w.z = pk2h(fmaxf(k1.x + q1.x, 0.f), fmaxf(k1.y + q1.y, 0.f));
            w.w = pk2h(fmaxf(k1.z + q1.z, 0.f), fmaxf(k1.w + q1.w, 0.f));
            dst[s * 256] = w;   // [s][wid][lane], s-stride = 4*64 uint4
        }
    };

    srow[t] = 0.f;        // cross-wave score accumulator
    stage(0, 0);
    __syncthreads();      // buffer 0 staged, srow zeroed

    for (int c = 0; c < nch; ++c) {
        int cur = c & 1;
        f32x4 acc[4][4] = {};

        // ---- s=0..3: resident B ----
#pragma unroll
        for (int s = 0; s < 4; ++s) {
#pragma unroll
            for (int mt = 0; mt < 4; ++mt) {
                U4H8 au;
                au.u = Afrag[cur][s][mt][lane];
#pragma unroll
                for (int nt = 0; nt < 4; ++nt) {
                    U4H8 bu;
                    bu.u = bfr0[nt][s];
                    acc[mt][nt] = __builtin_amdgcn_mfma_f32_16x16x32_f16(
                        au.v, bu.v, acc[mt][nt], 0, 0, 0);
                }
            }
        }

        // ---- s=4..7: streamed B with ping-pong prefetch (32-reg window) ----
        uint4 bst[2][4];
#pragma unroll
        for (int nt = 0; nt < 4; ++nt) bst[0][nt] = w2r[nt][16];  // s=4
#pragma unroll
        for (int s = 4; s < 8; ++s) {
            int pp = (s - 4) & 1;
            if (s < 7) {
#pragma unroll
                for (int nt = 0; nt < 4; ++nt)
                    bst[pp ^ 1][nt] = w2r[nt][(s + 1) * 4];
            }
#pragma unroll
            for (int mt = 0; mt < 4; ++mt) {
                U4H8 au;
                au.u = Afrag[cur][s][mt][lane];
#pragma unroll
                for (int nt = 0; nt < 4; ++nt) {
                    U4H8 bu;
                    bu.u = bst[pp][nt];
                    acc[mt][nt] = __builtin_amdgcn_mfma_f32_16x16x32_f16(
                        au.v, bu.v, acc[mt][nt], 0, 0, 0);
                }
            }
        }

        // stage next chunk (independent loads overlap epilogue VALU below)
        if (c + 1 < nch) stage(c + 1, cur ^ 1);

        // epilogue: relu(+b2) * W3, reduce over n-slice, cross-wave LDS add
#pragma unroll
        for (int mt = 0; mt < 4; ++mt) {
            float part[4];
#pragma unroll
            for (int r = 0; r < 4; ++r) {
                float pa = 0.f;
#pragma unroll
                for (int nt = 0; nt < 4; ++nt)
                    pa = fmaf(fmaxf(acc[mt][nt][r] + b2v[nt], 0.f), w3v[nt], pa);
                part[r] = pa;
            }
#pragma unroll
            for (int off = 1; off < 16; off <<= 1)
#pragma unroll
                for (int r = 0; r < 4; ++r)
                    part[r] += __shfl_xor(part[r], off, 64);
            if (col == 0)
#pragma unroll
                for (int r = 0; r < 4; ++r)
                    atomicAdd(&srow[c * 64 + mt * 16 + quad * 4 + r], part[r]);
        }
        __syncthreads();  // buf cur consumed, stage(c+1) done, atomics visible
    }

    // ---- masked softmax over srow ----
    float s = (t < klen) ? srow[t] : -3.4e38f;
    float m = s;
#pragma unroll
    for (int off = 1; off < 64; off <<= 1) m = fmaxf(m, __shfl_xor(m, off, 64));
    if (lane == 0) red[wid] = m;
    __syncthreads();
    m = fmaxf(fmaxf(red[0], red[1]), fmaxf(red[2], red[3]));
    float e = (t < klen) ? __expf(s - m) : 0.f;
    float sum = e;
#pragma unroll
    for (int off = 1; off < 64; off <<= 1) sum += __shfl_xor(sum, off, 64);
    if (lane == 0) red[4 + wid] = sum;
    __syncthreads();
    float denom = red[4] + red[5] + red[6] + red[7];
    srow[t] = e / denom;   // probs
    __syncthreads();

    // ---- PV: out[d=t] = sum_k probs[k] * keys[b][k][t] ----
    float acc = 0.f;
    const float* kp = keys + b * TK * DIM + t;  // coalesced: t = channel
#pragma unroll 8
    for (int k = 0; k < klen; ++k) acc = fmaf(srow[k], kp[k * DIM], acc);
    orow[t] = acc;
}

extern "C" void kernel_launch(void* const* d_in, const int* in_sizes, int n_in,
                              void* d_out, int out_size, void* d_ws, size_t ws_size,
                              hipStream_t stream) {
    (void)in_sizes; (void)n_in; (void)out_size; (void)ws_size;
    const float* queries = (const float*)d_in[0];
    const float* keys    = (const float*)d_in[1];
    const int*   qlens   = (const int*)d_in[2];
    const int*   klens   = (const int*)d_in[3];
    const float* W1      = (const float*)d_in[4];
    const float* b1      = (const float*)d_in[5];
    const float* W2      = (const float*)d_in[6];
    const float* b2      = (const float*)d_in[7];
    const float* W3      = (const float*)d_in[8];
    float* out = (float*)d_out;

    float* qh = (float*)d_ws;                     // 4*256*256 f32 = 1 MB (b1 folded)
    float* kh = qh + BATCH * TQ * HD;             // 1 MB
    unsigned short* W2T = (unsigned short*)(kh + BATCH * TK * HD);  // 128 KB

    prep_all<<<320, 256, 0, stream>>>(queries, keys, W1, b1, W2, qh, kh, W2T);
    mlp_attn<<<BATCH * TQ, 256, 0, stream>>>(
        qh, kh, W2T, b2, W3, keys, qlens, klens, out);
}

// Round 7
// 153.933 us; speedup vs baseline: 1.0373x; 1.0373x over previous
//
#include <hip/hip_runtime.h>
#include <cstdint>

#define BATCH 4
#define TQ 256
#define TK 256
#define DIM 256
#define HD 256

typedef _Float16 f16x8 __attribute__((ext_vector_type(8)));
typedef float f32x4 __attribute__((ext_vector_type(4)));

union U4H8 { uint4 u; f16x8 v; };

__device__ __forceinline__ unsigned short f2h(float f) {
    _Float16 h = (_Float16)f;
    unsigned short u;
    __builtin_memcpy(&u, &h, 2);
    return u;
}

__device__ __forceinline__ float h2f(unsigned short u) {
    _Float16 h;
    __builtin_memcpy(&h, &u, 2);
    return (float)h;
}

__device__ __forceinline__ uint32_t pk2h(float a, float b) {
    auto r = __builtin_amdgcn_cvt_pkrtz(a, b);
    uint32_t w;
    __builtin_memcpy(&w, &r, 4);
    return w;
}

// pack: blocks 0..511   -> X = [queries; keys] split to f16 hi/lo (Xh, Xl)
//       blocks 512..639 -> W1T hi/lo transpose: W1Th/l[n][k] = split(W1[k][n])
//       blocks 640..703 -> W2T[n][c] = (f16)W2[c][n]
__global__ __launch_bounds__(256) void pack(
    const float* __restrict__ queries, const float* __restrict__ keys,
    const float* __restrict__ W1, const float* __restrict__ W2,
    unsigned short* __restrict__ Xh, unsigned short* __restrict__ Xl,
    unsigned short* __restrict__ W1Th, unsigned short* __restrict__ W1Tl,
    unsigned short* __restrict__ W2T) {
    int i = blockIdx.x;
    int t = threadIdx.x;
    if (i < 512) {   // ---- X hi/lo split, 4 floats/thread ----
        const float* src = (i < 256 ? queries : keys) + (((i & 255) * 256 + t) << 2);
        float4 v = *(const float4*)src;
        uint32_t h0 = pk2h(v.x, v.y), h1 = pk2h(v.z, v.w);
        float f0 = h2f((unsigned short)h0), f1 = h2f((unsigned short)(h0 >> 16));
        float f2 = h2f((unsigned short)h1), f3 = h2f((unsigned short)(h1 >> 16));
        uint32_t l0 = pk2h(v.x - f0, v.y - f1), l1 = pk2h(v.z - f2, v.w - f3);
        int o = i * 256 + t;
        ((uint2*)Xh)[o] = make_uint2(h0, h1);
        ((uint2*)Xl)[o] = make_uint2(l0, l1);
        return;
    }
    __shared__ float tile[32][33];
    int tx = t & 31, ty = t >> 5;
    if (i < 640) {   // ---- W1 transpose + hi/lo split: [512][256] -> [256][512] ----
        int bi = i - 512;
        int kt = (bi >> 3) * 32, nt = (bi & 7) * 32;
#pragma unroll
        for (int r = 0; r < 4; ++r)
            tile[ty + r * 8][tx] = W1[(kt + ty + r * 8) * HD + nt + tx];
        __syncthreads();
#pragma unroll
        for (int r = 0; r < 4; ++r) {
            float v = tile[tx][ty + r * 8];
            unsigned short h = f2h(v);
            int o = (nt + ty + r * 8) * 512 + kt + tx;
            W1Th[o] = h;
            W1Tl[o] = f2h(v - h2f(h));
        }
        return;
    }
    // ---- W2 transpose -> f16 ----
    int bi = i - 640;
    int tc = (bi & 7) * 32, tn = (bi >> 3) * 32;
#pragma unroll
    for (int r = 0; r < 4; ++r)
        tile[ty + r * 8][tx] = W2[(tc + ty + r * 8) * HD + tn + tx];
    __syncthreads();
#pragma unroll
    for (int r = 0; r < 4; ++r)
        W2T[(tn + ty + r * 8) * HD + tc + tx] = f2h(tile[tx][ty + r * 8]);
}

// qkh[m][n] (m<1024: qh rows w/ b1 folded; else kh rows) via MFMA with
// 3-term hi/lo split (AhBh + AlBh + AhBl) -> effectively fp32-exact.
// Block = 64 m-rows x 64 n-cols; wave = 16 m-rows. Grid 32x4 = 128.
__global__ __launch_bounds__(256) void prep_mfma(
    const unsigned short* __restrict__ Xh, const unsigned short* __restrict__ Xl,
    const unsigned short* __restrict__ W1Th, const unsigned short* __restrict__ W1Tl,
    const float* __restrict__ b1, float* __restrict__ qkh) {
    int mblk = blockIdx.x >> 2, nblk = blockIdx.x & 3;
    int t = threadIdx.x, wid = t >> 6, lane = t & 63;
    int col = lane & 15, quad = lane >> 4;
    int arow = mblk * 64 + wid * 16 + col;
    bool isQ = mblk < 16;
    int koff = isQ ? 256 : 0;   // queries use W1 rows 256..511

    const uint4* axh = (const uint4*)(Xh + arow * DIM) + quad;  // +quad: k-octet
    const uint4* axl = (const uint4*)(Xl + arow * DIM) + quad;
    const uint4* pbh[4];
    const uint4* pbl[4];
    float b1v[4];
#pragma unroll
    for (int nt = 0; nt < 4; ++nt) {
        int n = nblk * 64 + nt * 16 + col;
        pbh[nt] = (const uint4*)(W1Th + n * 512 + koff) + quad;
        pbl[nt] = (const uint4*)(W1Tl + n * 512 + koff) + quad;
        b1v[nt] = isQ ? b1[n] : 0.f;
    }
    f32x4 acc[4] = {};
#pragma unroll
    for (int s = 0; s < 8; ++s) {
        U4H8 ah, al;
        ah.u = axh[s * 4];
        al.u = axl[s * 4];
#pragma unroll
        for (int nt = 0; nt < 4; ++nt) {
            U4H8 bh, bl;
            bh.u = pbh[nt][s * 4];
            bl.u = pbl[nt][s * 4];
            acc[nt] = __builtin_amdgcn_mfma_f32_16x16x32_f16(ah.v, bh.v, acc[nt], 0, 0, 0);
            acc[nt] = __builtin_amdgcn_mfma_f32_16x16x32_f16(al.v, bh.v, acc[nt], 0, 0, 0);
            acc[nt] = __builtin_amdgcn_mfma_f32_16x16x32_f16(ah.v, bl.v, acc[nt], 0, 0, 0);
        }
    }
#pragma unroll
    for (int nt = 0; nt < 4; ++nt)
#pragma unroll
        for (int r = 0; r < 4; ++r)
            qkh[(mblk * 64 + wid * 16 + quad * 4 + r) * HD + nblk * 64 + nt * 16 + col] =
                acc[nt][r] + b1v[nt];
}

// One block per (b,q). Single-buffer LDS A (32 KB -> 4 blocks/CU by LDS),
// B streamed from L1/L2 with 1-step prefetch. Then softmax + PV in-block.
__global__ __launch_bounds__(256, 3) void mlp_attn(
    const float* __restrict__ qh, const float* __restrict__ kh,
    const unsigned short* __restrict__ W2T,
    const float* __restrict__ b2, const float* __restrict__ W3,
    const float* __restrict__ keys,
    const int* __restrict__ qlens, const int* __restrict__ klens,
    float* __restrict__ out) {
    int bid = blockIdx.x;
    int b = bid >> 8;
    int q = bid & 255;
    int t = threadIdx.x;
    float* orow = out + (b * TQ + q) * DIM;
    if (q >= qlens[b]) { orow[t] = 0.f; return; }   // uniform exit, zero row
    int klen = klens[b];
    int nch = (klen + 63) >> 6;   // 2..4 valid 64-wide k chunks

    __shared__ uint4 Afrag[8][4][64];   // single buffer, 32 KB
    __shared__ float srow[TK];
    __shared__ float red[8];

    int wid = t >> 6, lane = t & 63;
    int col = lane & 15, quad = lane >> 4;

    int nb = wid * 64;
    const uint4* w2r[4];
    float b2v[4], w3v[4];
#pragma unroll
    for (int nt = 0; nt < 4; ++nt) {
        int n = nb + nt * 16 + col;
        w2r[nt] = (const uint4*)(W2T + n * HD) + quad;  // pre-offset by c-octet
        b2v[nt] = b2[n];
        w3v[nt] = W3[n];
    }

    // staging role: row p = wid*16+col, octet quad (writer lane == frag slot)
    int p = (wid << 4) | col;
    const float* qrow = qh + (b * TQ + q) * HD + quad * 8;  // b1 pre-folded
    const float* kbase = kh + (b * TK) * HD + quad * 8;

    srow[t] = 0.f;

    for (int c = 0; c < nch; ++c) {
        if (c) __syncthreads();     // prior compute done before overwrite
        {   // ---- stage chunk c ----
            const float* krow = kbase + (c * 64 + p) * HD;
            uint4* dst = &Afrag[0][wid][lane];
#pragma unroll 2
            for (int s = 0; s < 8; ++s) {
                const float4 k0 = *(const float4*)(krow + s * 32);
                const float4 k1 = *(const float4*)(krow + s * 32 + 4);
                const float4 q0 = *(const float4*)(qrow + s * 32);
                const float4 q1 = *(const float4*)(qrow + s * 32 + 4);
                uint4 w;
                w.x = pk2h(fmaxf(k0.x + q0.x, 0.f), fmaxf(k0.y + q0.y, 0.f));
                w.y = pk2h(fmaxf(k0.z + q0.z, 0.f), fmaxf(k0.w + q0.w, 0.f));
                w.z = pk2h(fmaxf(k1.x + q1.x, 0.f), fmaxf(k1.y + q1.y, 0.f));
                w.w = pk2h(fmaxf(k1.z + q1.z, 0.f), fmaxf(k1.w + q1.w, 0.f));
                dst[s * 256] = w;
            }
        }
        __syncthreads();            // A tile visible

        f32x4 acc[4][4] = {};
        uint4 bst[2][4];
#pragma unroll
        for (int nt = 0; nt < 4; ++nt) bst[0][nt] = w2r[nt][0];
#pragma unroll
        for (int s = 0; s < 8; ++s) {
            int pp = s & 1;
            if (s < 7) {
#pragma unroll
                for (int nt = 0; nt < 4; ++nt)
                    bst[pp ^ 1][nt] = w2r[nt][(s + 1) * 4];
            }
#pragma unroll
            for (int mt = 0; mt < 4; ++mt) {
                U4H8 au;
                au.u = Afrag[s][mt][lane];
#pragma unroll
                for (int nt = 0; nt < 4; ++nt) {
                    U4H8 bu;
                    bu.u = bst[pp][nt];
                    acc[mt][nt] = __builtin_amdgcn_mfma_f32_16x16x32_f16(
                        au.v, bu.v, acc[mt][nt], 0, 0, 0);
                }
            }
        }

        // epilogue: relu(+b2) * W3, n-reduce (shfl within wave, atomic across)
#pragma unroll
        for (int mt = 0; mt < 4; ++mt) {
            float part[4];
#pragma unroll
            for (int r = 0; r < 4; ++r) {
                float pa = 0.f;
#pragma unroll
                for (int nt = 0; nt < 4; ++nt)
                    pa = fmaf(fmaxf(acc[mt][nt][r] + b2v[nt], 0.f), w3v[nt], pa);
                part[r] = pa;
            }
#pragma unroll
            for (int off = 1; off < 16; off <<= 1)
#pragma unroll
                for (int r = 0; r < 4; ++r)
                    part[r] += __shfl_xor(part[r], off, 64);
            if (col == 0)
#pragma unroll
                for (int r = 0; r < 4; ++r)
                    atomicAdd(&srow[c * 64 + mt * 16 + quad * 4 + r], part[r]);
        }
    }
    __syncthreads();   // all chunks' atomics visible

    // ---- masked softmax over srow ----
    float s = (t < klen) ? srow[t] : -3.4e38f;
    float m = s;
#pragma unroll
    for (int off = 1; off < 64; off <<= 1) m = fmaxf(m, __shfl_xor(m, off, 64));
    if (lane == 0) red[wid] = m;
    __syncthreads();
    m = fmaxf(fmaxf(red[0], red[1]), fmaxf(red[2], red[3]));
    float e = (t < klen) ? __expf(s - m) : 0.f;
    float sum = e;
#pragma unroll
    for (int off = 1; off < 64; off <<= 1) sum += __shfl_xor(sum, off, 64);
    if (lane == 0) red[4 + wid] = sum;
    __syncthreads();
    float denom = red[4] + red[5] + red[6] + red[7];
    srow[t] = e / denom;   // probs
    __syncthreads();

    // ---- PV: out[d=t] = sum_k probs[k] * keys[b][k][t] ----
    float acc = 0.f;
    const float* kp = keys + b * TK * DIM + t;  // coalesced: t = channel
#pragma unroll 16
    for (int k = 0; k < klen; ++k) acc = fmaf(srow[k], kp[k * DIM], acc);
    orow[t] = acc;
}

extern "C" void kernel_launch(void* const* d_in, const int* in_sizes, int n_in,
                              void* d_out, int out_size, void* d_ws, size_t ws_size,
                              hipStream_t stream) {
    (void)in_sizes; (void)n_in; (void)out_size; (void)ws_size;
    const float* queries = (const float*)d_in[0];
    const float* keys    = (const float*)d_in[1];
    const int*   qlens   = (const int*)d_in[2];
    const int*   klens   = (const int*)d_in[3];
    const float* W1      = (const float*)d_in[4];
    const float* b1      = (const float*)d_in[5];
    const float* W2      = (const float*)d_in[6];
    const float* b2      = (const float*)d_in[7];
    const float* W3      = (const float*)d_in[8];
    float* out = (float*)d_out;

    // ws layout (16B-aligned chunks)
    float* qkh = (float*)d_ws;                         // 2048*256 f32 = 2 MB
    float* qh = qkh;                                   // rows 0..1023
    float* kh = qkh + 1024 * HD;                       // rows 1024..2047
    unsigned short* Xh   = (unsigned short*)(qkh + 2048 * HD);   // 1 MB
    unsigned short* Xl   = Xh + 2048 * DIM;                      // 1 MB
    unsigned short* W1Th = Xl + 2048 * DIM;                      // 256 KB
    unsigned short* W1Tl = W1Th + 256 * 512;                     // 256 KB
    unsigned short* W2T  = W1Tl + 256 * 512;                     // 128 KB

    pack<<<704, 256, 0, stream>>>(queries, keys, W1, W2, Xh, Xl, W1Th, W1Tl, W2T);
    prep_mfma<<<128, 256, 0, stream>>>(Xh, Xl, W1Th, W1Tl, b1, qkh);
    mlp_attn<<<BATCH * TQ, 256, 0, stream>>>(
        qh, kh, W2T, b2, W3, keys, qlens, klens, out);
}